// Round 7
// baseline (381.845 us; speedup 1.0000x reference)
//
#include <hip/hip_runtime.h>
#include <stdint.h>

// Word2MatEncoder: out[b] = prod_{s=0..63} table[sent[b,s]]  (28x28 fp32 chain)
//
// R7: remove the ~2000 cyc/step intra-wave stall of R5 (barrier drains +
// vmcnt(0) DMA drain). Block = 1 wave -> no __syncthreads at all. The B
// matrix lives in TWO separate __shared__ objects (rows 0-13 in ldsLo,
// rows 14-27 in ldsHi); while FMA-ing one half of M_s we DMA the same half
// of M_{s+1} into the *other* object region just consumed. At every MATMUL
// the in-flight DMA targets the other LDS object -> no alias drains; halves
// are sequenced by explicit s_waitcnt vmcnt(14/15) (never 0 mid-loop).
// Geometry: 7 lanes x 4 rows per task, 9 tasks/wave (RPL=4 minimizes LDS
// read traffic; FMA floor 6272 cyc/step dominates). Gather index for step
// s+1 prefetched into a scalar during step s-1 so per-step vmem = exactly
// 28 DMA loads + 1 idx load (gather) and the vmcnt counts stay exact.
// fp32 throughout (no fp32 MFMA on CDNA4; bf16 error compounds over 63 muls).

#define D 28
#define EMB 784
#define SEQ 64
#define NITEMS 2048
#define LPI 7            // lanes per task
#define IPW 9            // tasks per wave (63 of 64 lanes active)
#define RPL 4            // rows of the running product per lane
#define HROWS 14         // rows per half-buffer
#define CHUNK_F 256      // floats per row-chunk (64 lanes x 16B)
#define HBUF_F (HROWS * CHUNK_F)  // 3584 floats = 14336 B per half

typedef __attribute__((address_space(3))) uint32_t lds_u32;
typedef const __attribute__((address_space(1))) uint32_t glb_u32;

// DMA 14 rows (one half-matrix per slot) into a half-buffer. gl = matrix
// base + half-offset + rl*16B. Row r of the half lands at half + r*CHUNK_F,
// lane l writing its 16B at l*16 (HW rule): slot s's row floats at s*28.
__device__ __forceinline__ void dma_half(const float* gl, float* half) {
#pragma unroll
  for (int t = 0; t < HROWS; ++t)
    __builtin_amdgcn_global_load_lds((glb_u32*)(gl + t * D),
                                     (lds_u32*)(half + t * CHUNK_F), 16, 0, 0);
}

// Half-matmul: Cc[r][:] (+)= Aa[r][k] * Brow_k for k in [K0, K0+14).
// Bp points at this slot's columns inside the half-buffer (k index local).
#define MMH(Aa, Cc, Bp, K0)                                                    \
  do {                                                                         \
    _Pragma("unroll") for (int kk = 0; kk < HROWS; ++kk) {                     \
      _Pragma("unroll") for (int jv = 0; jv < 7; ++jv) {                       \
        float4 m = *(const float4*)((Bp) + kk * CHUNK_F + 4 * jv);             \
        _Pragma("unroll") for (int r = 0; r < RPL; ++r) {                      \
          float a = Aa[r][(K0) + kk];                                          \
          if ((K0) + kk == 0) {                                                \
            Cc[r][4 * jv + 0] = a * m.x;                                       \
            Cc[r][4 * jv + 1] = a * m.y;                                       \
            Cc[r][4 * jv + 2] = a * m.z;                                       \
            Cc[r][4 * jv + 3] = a * m.w;                                       \
          } else {                                                             \
            Cc[r][4 * jv + 0] = fmaf(a, m.x, Cc[r][4 * jv + 0]);               \
            Cc[r][4 * jv + 1] = fmaf(a, m.y, Cc[r][4 * jv + 1]);               \
            Cc[r][4 * jv + 2] = fmaf(a, m.z, Cc[r][4 * jv + 2]);               \
            Cc[r][4 * jv + 3] = fmaf(a, m.w, Cc[r][4 * jv + 3]);               \
          }                                                                    \
        }                                                                      \
      }                                                                        \
    }                                                                          \
  } while (0)

// waitcnt simm16 (gfx9): vmcnt[3:0]=bits[3:0], exp=bits[6:4], lgkm=bits[11:8],
// vmcnt[5:4]=bits[15:14]. lgkm/exp set to no-wait (15/7).
#define WAIT_VM0 0x0F70   // vmcnt(0)
#define WAIT_VM14 0x0F7E  // vmcnt(14)
#define WAIT_VM15 0x0F7F  // vmcnt(15)

// One chain step. On entry: halves of M_s are the newest DMA groups in
// flight (plus, for gather, one idx load newer still). LAST is literal 0/1.
#define STEPX(Aa, Cc, LAST)                                                    \
  do {                                                                         \
    __builtin_amdgcn_s_waitcnt(GATHER ? WAIT_VM15 : WAIT_VM14); /* lo(M_s) */  \
    MMH(Aa, Cc, Blo, 0);                                                       \
    if (LAST) {                                                                \
      __builtin_amdgcn_s_waitcnt(WAIT_VM0); /* hi(M_s) (drain all) */          \
      MMH(Aa, Cc, Bhi, HROWS);                                                 \
    } else {                                                                   \
      const float* gnx = GATHER ? src + (size_t)idxn * EMB + rl * 4            \
                                : src + ((size_t)task * SEG_LEN + s + 1) * EMB \
                                      + rl * 4;                                \
      dma_half(gnx, ldsLo); /* lo(M_{s+1}) overwrites consumed lo */           \
      __builtin_amdgcn_s_waitcnt(WAIT_VM14); /* hi(M_s) ready */               \
      MMH(Aa, Cc, Bhi, HROWS);                                                 \
      dma_half(gnx + HROWS * D, ldsHi); /* hi(M_{s+1}) */                      \
      if (GATHER) idxn = spl[(s + 2 < SEG_LEN) ? s + 2 : SEG_LEN - 1];         \
    }                                                                          \
    ++s;                                                                       \
  } while (0)

// Product of SEG_LEN consecutive matrices (SEG_LEN-1 odd -> result in A1).
// GATHER: matrices are table[spl[s]]; else dense at src + (task*SEG_LEN+s)*EMB.
template <int SEG_LEN, int PSEG, bool GATHER>
__global__ __launch_bounds__(64, 1) void chain_kernel(
    const float* __restrict__ src, const int* __restrict__ sent,
    float* __restrict__ dst, int ntask) {
  __shared__ __align__(16) float ldsLo[HBUF_F];
  __shared__ __align__(16) float ldsHi[HBUF_F];

  const int lane = threadIdx.x;
  int slot = lane / LPI;
  int rl = lane - slot * LPI;
  if (slot >= IPW) { slot = IPW - 1; rl = LPI - 1; }  // lane 63 mirrors lane 62
  int task = blockIdx.x * IPW + slot;
  if (task >= ntask) task = ntask - 1;  // tail duplicates (same values, benign)

  const int* spl = nullptr;
  if (GATHER) {
    const int item = task / PSEG;
    const int seg = task - item * PSEG;
    spl = sent + item * SEQ + seg * SEG_LEN;
  }

  float A0[RPL][D], A1[RPL][D];

  // A0 = this lane's rows (rl*4 .. rl*4+3) of the first matrix (direct loads)
  {
    const float* m0 = GATHER ? src + (size_t)spl[0] * EMB
                             : src + (size_t)task * SEG_LEN * EMB;
#pragma unroll
    for (int r = 0; r < RPL; ++r) {
      const float* rp = m0 + (rl * RPL + r) * D;
#pragma unroll
      for (int jv = 0; jv < 7; ++jv) {
        float4 v = *(const float4*)(rp + 4 * jv);
        A0[r][4 * jv + 0] = v.x;
        A0[r][4 * jv + 1] = v.y;
        A0[r][4 * jv + 2] = v.z;
        A0[r][4 * jv + 3] = v.w;
      }
    }
  }

  // stage matrix 1 (both halves); prefetch idx for matrix 2 (gather)
  {
    const float* g1 = GATHER ? src + (size_t)spl[1] * EMB + rl * 4
                             : src + ((size_t)task * SEG_LEN + 1) * EMB + rl * 4;
    dma_half(g1, ldsLo);
    dma_half(g1 + HROWS * D, ldsHi);
  }
  int idxn = 0;
  if (GATHER) idxn = spl[(2 < SEG_LEN) ? 2 : SEG_LEN - 1];

  const float* Blo = ldsLo + slot * (LPI * 4);  // slot*28 floats
  const float* Bhi = ldsHi + slot * (LPI * 4);

  int s = 1;
#pragma unroll 1
  for (int p = 0; p < (SEG_LEN - 1) / 2; ++p) {
    STEPX(A0, A1, 0);
    STEPX(A1, A0, 0);
  }
  STEPX(A0, A1, 1);  // final step (SEG_LEN-1 odd) -> result in A1

  // store
  {
    float* op = dst + (size_t)task * EMB;
#pragma unroll
    for (int r = 0; r < RPL; ++r) {
      float* rp = op + (rl * RPL + r) * D;
#pragma unroll
      for (int jv = 0; jv < 7; ++jv) {
        *(float4*)(rp + 4 * jv) =
            make_float4(A1[r][4 * jv + 0], A1[r][4 * jv + 1],
                        A1[r][4 * jv + 2], A1[r][4 * jv + 3]);
      }
    }
  }
}

extern "C" void kernel_launch(void* const* d_in, const int* in_sizes, int n_in,
                              void* d_out, int out_size, void* d_ws, size_t ws_size,
                              hipStream_t stream) {
  const float* table = (const float*)d_in[0];
  const int* sent = (const int*)d_in[1];
  float* out = (float*)d_out;

  const size_t need4 = (size_t)NITEMS * 4 * EMB * sizeof(float);  // 25.7 MB
  if (ws_size >= need4) {
    float* p = (float*)d_ws;
    // phase 1: 4 segments of 16 per item -> 8192 partials (contiguous per item)
    const int ntask1 = NITEMS * 4;
    chain_kernel<16, 4, true><<<(ntask1 + IPW - 1) / IPW, 64, 0, stream>>>(
        table, sent, p, ntask1);
    // phase 2: chain each item's 4 partials -> d_out
    chain_kernel<4, 1, false><<<(NITEMS + IPW - 1) / IPW, 64, 0, stream>>>(
        p, nullptr, out, NITEMS);
  } else {
    // fallback: direct 64-long chain per item straight into d_out
    chain_kernel<64, 1, true><<<(NITEMS + IPW - 1) / IPW, 64, 0, stream>>>(
        table, sent, out, NITEMS);
  }
}